// Round 7
// baseline (184.177 us; speedup 1.0000x reference)
//
#include <hip/hip_runtime.h>
#include <hip/hip_bf16.h>
#include <stdint.h>

typedef __bf16 bf16x8 __attribute__((ext_vector_type(8)));
typedef __bf16 bf16x4 __attribute__((ext_vector_type(4)));
typedef float  f32x4  __attribute__((ext_vector_type(4)));
typedef short  s16x4  __attribute__((ext_vector_type(4)));
typedef unsigned short u16_t;

#define MFMA(a, b, c)   __builtin_amdgcn_mfma_f32_16x16x32_bf16((a), (b), (c), 0, 0, 0)
#define MFMA16(a, b, c) __builtin_amdgcn_mfma_f32_16x16x16bf16_1k((a), (b), (c), 0, 0, 0)

// async global->LDS, 16B per lane; LDS dest is wave-uniform base + lane*16
__device__ __forceinline__ void cp16(const void* g, void* l) {
  __builtin_amdgcn_global_load_lds(
      (const __attribute__((address_space(1))) unsigned int*)g,
      (__attribute__((address_space(3))) unsigned int*)l, 16, 0, 0);
}

// ---------------- kernel 1: fused x-convert + W-transpose-convert ----------------
__global__ __launch_bounds__(256) void k_prep(const float* __restrict__ x,
                                              const float* __restrict__ W0,
                                              const float* __restrict__ W1,
                                              const float* __restrict__ W2,
                                              u16_t* __restrict__ xb,
                                              u16_t* __restrict__ Wt) {
  __shared__ u16_t T[64][65];
  int bx = blockIdx.x, t = threadIdx.x;
  if (bx < 4096) {
    int i = bx * 256 + t;
    float4 f = ((const float4*)x)[i];
    bf16x4 o = {(__bf16)f.x, (__bf16)f.y, (__bf16)f.z, (__bf16)f.w};
    *(bf16x4*)&xb[(size_t)i * 4] = o;
    return;
  }
  int j = bx - 4096;
  int nx = j & 15, ny = (j >> 4) & 15, z = j >> 8;
  const float* W = z == 0 ? W0 : (z == 1 ? W1 : W2);
  int k0 = ny * 64, n0 = nx * 64;
#pragma unroll
  for (int i = 0; i < 16; i++) {
    int e = i * 256 + t, r = e >> 6, c = e & 63;
    __bf16 hv = (__bf16)W[(size_t)(k0 + r) * 1024 + n0 + c];
    T[r][c] = *(u16_t*)&hv;
  }
  __syncthreads();
  size_t base = ((size_t)z * 1024 + n0) * 1024 + k0;
#pragma unroll
  for (int i = 0; i < 16; i++) {
    int e = i * 256 + t, r = e >> 6, c = e & 63;
    Wt[base + (size_t)r * 1024 + c] = T[c][r];
  }
}

// ---------------- kernel 2: fused QKV GEMM (m97 structure) ----------------
__global__ __launch_bounds__(256) void k_gemm_qkv(
    const u16_t* __restrict__ A, const u16_t* __restrict__ Bt,
    const float* __restrict__ bq, const float* __restrict__ bk,
    const float* __restrict__ bv,
    u16_t* __restrict__ Qo, u16_t* __restrict__ Ko, u16_t* __restrict__ Vo) {
  __shared__ u16_t As[128 * 32];
  __shared__ u16_t Bs[128 * 32];
  const int tid = threadIdx.x, lane = tid & 63, wv = tid >> 6;
  const int quad = lane >> 4, col = lane & 15;
  const int wm = wv >> 1, wn = wv & 1;
  const int tn = blockIdx.x * 128, tm = blockIdx.y * 128;
  f32x4 acc[4][4] = {};

  const int c0 = wv * 2;
  const int srow = lane >> 2;
  const int spc = lane & 3;

  for (int kk = 0; kk < 1024; kk += 32) {
#pragma unroll
    for (int i = 0; i < 2; i++) {
      int c = c0 + i;
      int m = c * 16 + srow;
      int lch = spc ^ ((m >> 1) & 3);
      cp16(A + (size_t)(tm + m) * 1024 + kk + lch * 8, As + c * 512 + lane * 8);
      cp16(Bt + (size_t)(tn + m) * 1024 + kk + lch * 8, Bs + c * 512 + lane * 8);
    }
    __syncthreads();
    bf16x8 af[4], bfv[4];
#pragma unroll
    for (int mt = 0; mt < 4; mt++) {
      int row = wm * 64 + mt * 16 + col;
      af[mt] = *(const bf16x8*)&As[row * 32 + (quad ^ ((row >> 1) & 3)) * 8];
    }
#pragma unroll
    for (int nt = 0; nt < 4; nt++) {
      int row = wn * 64 + nt * 16 + col;
      bfv[nt] = *(const bf16x8*)&Bs[row * 32 + (quad ^ ((row >> 1) & 3)) * 8];
    }
#pragma unroll
    for (int mt = 0; mt < 4; mt++)
#pragma unroll
      for (int nt = 0; nt < 4; nt++)
        acc[mt][nt] = MFMA(af[mt], bfv[nt], acc[mt][nt]);
    __syncthreads();
  }

  const int mat = tn >> 10;
  const float* bias = mat == 0 ? bq : (mat == 1 ? bk : bv);
  if (mat == 2) {
#pragma unroll
    for (int nt = 0; nt < 4; nt++) {
      int gn = tn + wn * 64 + nt * 16 + col;
      int d = gn & 1023, h = d >> 6, dk = d & 63;
      float bb = bias[d];
#pragma unroll
      for (int mt = 0; mt < 4; mt++) {
        int gm = tm + wm * 64 + mt * 16 + quad * 4;
        int b = gm >> 11, s = gm & 2047;
        bf16x4 pk4;
#pragma unroll
        for (int r = 0; r < 4; r++) pk4[r] = (__bf16)(acc[mt][nt][r] + bb);
        *(bf16x4*)&Vo[((size_t)((b * 16 + h) * 64 + dk)) * 2048 + s] = pk4;
      }
    }
  } else {
    u16_t* O = mat == 0 ? Qo : Ko;
    const float scl = mat == 0 ? 0.18033688011112042f : 1.0f;  // log2(e)/8 in Q
#pragma unroll
    for (int nt = 0; nt < 4; nt++) {
      int gn = tn + wn * 64 + nt * 16 + col;
      int d = gn & 1023, h = d >> 6, dk = d & 63;
      float bb = bias[d];
#pragma unroll
      for (int mt = 0; mt < 4; mt++) {
#pragma unroll
        for (int r = 0; r < 4; r++) {
          int gm = tm + wm * 64 + mt * 16 + quad * 4 + r;
          int b = gm >> 11, s = gm & 2047;
          __bf16 hv = (__bf16)((acc[mt][nt][r] + bb) * scl);
          O[((size_t)((b * 16 + h) * 2048 + s)) * 64 + dk] = *(u16_t*)&hv;
        }
      }
    }
  }
}

// ---------------- kernel 3: fused attention (v7, barrier-free K-loop) ----------------
// 2 waves/block. q-tile 64 shared; wave kh privately owns keys [kh*1024,+1024)
// in 32 stages of 32 keys, staged into its OWN 16 KB LDS ring (ring-2).
// Sync = per-wave asm s_waitcnt vmcnt(8) only: waits for the PREVIOUS stage's
// loads, never the fresh prefetch. No __syncthreads until the final kh-merge.
__global__ __launch_bounds__(128, 3) void k_attn(const u16_t* __restrict__ Q,
                                                 const u16_t* __restrict__ K,
                                                 const u16_t* __restrict__ Vt,
                                                 float* __restrict__ out) {
  __shared__ u16_t smem[16384];        // 32 KB: per-wave 8192 hw = [K0|K1|V0|V1]
  const int tid = threadIdx.x, lane = tid & 63, kh = tid >> 6;
  const int quad = lane >> 4, col = lane & 15;

  // XCD-swizzled grid: bid&7 = XCD, 4 heads per XCD (2 MB K/V -> fits 4 MB L2)
  const int bid = blockIdx.x;
  const int bh = (bid & 7) + 8 * ((bid >> 3) >> 5);
  const int qt = (bid >> 3) & 31;
  const int b = bh >> 4, h = bh & 15;

  u16_t* wbase = smem + kh * 8192;
  const u16_t* Qg = Q + ((size_t)bh * 2048 + qt * 64) * 64;
  const u16_t* Kg = K + ((size_t)bh * 2048 + kh * 1024) * 64;  // wave's key range
  const u16_t* Vg = Vt + (size_t)bh * 64 * 2048 + kh * 1024;

  // Q fragments FIRST (so their vmcnt drain doesn't touch cp16s)
  bf16x8 qf[4][2];
#pragma unroll
  for (int nt = 0; nt < 4; nt++)
#pragma unroll
    for (int ks = 0; ks < 2; ks++)
      qf[nt][ks] = *(const bf16x8*)&Qg[(size_t)(nt * 16 + col) * 64 + ks * 32 + quad * 8];

  // staging geometry (K: psi=row&7; V: phi=(row>>1)&3 — both measured conflict-free)
  const int kr = lane >> 3, kc = (lane & 7) ^ (lane >> 3);        // K tile [32k][64hw]
  const int vr = lane >> 2, vc = (lane & 3) ^ ((lane >> 3) & 3);  // V tile [64d][32hw]

  // stage 0 into buffer 0
#pragma unroll
  for (int sl = 0; sl < 4; sl++) {
    cp16(Kg + (size_t)(sl * 8 + kr) * 64 + kc * 8, wbase + sl * 512 + lane * 8);
    cp16(Vg + (size_t)(sl * 16 + vr) * 2048 + vc * 8, wbase + 4096 + sl * 512 + lane * 8);
  }

  const short one_bf = (short)0x3F80;
  s16x4 ones4 = {one_bf, one_bf, one_bf, one_bf};

  f32x4 ao[4][4] = {};
  f32x4 dn[4] = {};

#pragma unroll 2
  for (int kt = 0; kt < 32; kt++) {
    const int cur = kt & 1;
    u16_t* Kb = wbase + cur * 2048;
    u16_t* Vb = wbase + 4096 + cur * 2048;

    // prefetch stage kt+1 into other buffer, then wait ONLY for stage kt's 8
    if (kt + 1 < 32) {
      u16_t* Kn = wbase + (cur ^ 1) * 2048;
      u16_t* Vn = wbase + 4096 + (cur ^ 1) * 2048;
#pragma unroll
      for (int sl = 0; sl < 4; sl++) {
        cp16(Kg + (size_t)((kt + 1) * 32 + sl * 8 + kr) * 64 + kc * 8,
             Kn + sl * 512 + lane * 8);
        cp16(Vg + (size_t)(sl * 16 + vr) * 2048 + (kt + 1) * 32 + vc * 8,
             Vn + sl * 512 + lane * 8);
      }
      asm volatile("s_waitcnt vmcnt(8)" ::: "memory");
    } else {
      asm volatile("s_waitcnt vmcnt(0)" ::: "memory");
    }

    // S^T = K @ Q^T : 32k x 64q  (A=K-frag rows=keys, B=Q-frag)
    f32x4 sc[2][4] = {};
#pragma unroll
    for (int ks = 0; ks < 2; ks++) {
      bf16x8 kf[2];
#pragma unroll
      for (int mt = 0; mt < 2; mt++) {
        int row = mt * 16 + col;
        kf[mt] = *(const bf16x8*)&Kb[row * 64 + (((ks * 4 + quad) ^ (row & 7)) * 8)];
      }
#pragma unroll
      for (int mt = 0; mt < 2; mt++)
#pragma unroll
        for (int nt = 0; nt < 4; nt++)
          sc[mt][nt] = MFMA(kf[mt], qf[nt][ks], sc[mt][nt]);
    }

    // P = exp2(S^T) in-register -> A-fragment of 16x16x16 (round-5 identity)
    s16x4 pf[2][4];
#pragma unroll
    for (int mt = 0; mt < 2; mt++)
#pragma unroll
      for (int nt = 0; nt < 4; nt++) {
#pragma unroll
        for (int r = 0; r < 4; r++) {
          __bf16 e = (__bf16)__builtin_amdgcn_exp2f(sc[mt][nt][r]);
          pf[mt][nt][r] = *(short*)&e;
        }
        dn[nt] = MFMA16(pf[mt][nt], ones4, dn[nt]);
      }

    // O += P @ V  (V^T tile rows d, b64 = 4 consecutive keys per lane)
#pragma unroll
    for (int mt = 0; mt < 2; mt++) {
#pragma unroll
      for (int dt = 0; dt < 4; dt++) {
        int d = dt * 16 + col;
        int phys = (mt * 2 + (quad >> 1)) ^ ((col >> 1) & 3);
        s16x4 vf = *(const s16x4*)&Vb[d * 32 + phys * 8 + (quad & 1) * 4];
#pragma unroll
        for (int nt = 0; nt < 4; nt++)
          ao[nt][dt] = MFMA16(pf[mt][nt], vf, ao[nt][dt]);
      }
    }
  }

  // kh-merge: first (and only) block barrier
  float* red = (float*)smem;
  const int rb = lane * 81;
  __syncthreads();
  if (kh == 1) {
#pragma unroll
    for (int nt = 0; nt < 4; nt++) {
#pragma unroll
      for (int dt = 0; dt < 4; dt++)
#pragma unroll
        for (int r = 0; r < 4; r++)
          red[rb + (nt * 4 + dt) * 4 + r] = ao[nt][dt][r];
#pragma unroll
      for (int r = 0; r < 4; r++)
        red[rb + 64 + nt * 4 + r] = dn[nt][r];
    }
  }
  __syncthreads();
  if (kh == 0) {
#pragma unroll
    for (int nt = 0; nt < 4; nt++) {
      float dsum[4];
#pragma unroll
      for (int r = 0; r < 4; r++)
        dsum[r] = dn[nt][r] + red[rb + 64 + nt * 4 + r] + 1e-8f;
#pragma unroll
      for (int dt = 0; dt < 4; dt++) {
#pragma unroll
        for (int r = 0; r < 4; r++) {
          float v = (ao[nt][dt][r] + red[rb + (nt * 4 + dt) * 4 + r]) / dsum[r];
          int s = qt * 64 + nt * 16 + quad * 4 + r;
          out[((size_t)b * 2048 + s) * 1024 + h * 64 + dt * 16 + col] = v;
        }
      }
    }
  }
}

// ---------------- launcher ----------------
extern "C" void kernel_launch(void* const* d_in, const int* in_sizes, int n_in,
                              void* d_out, int out_size, void* d_ws, size_t ws_size,
                              hipStream_t stream) {
  const float* x  = (const float*)d_in[0];
  const float* Wq = (const float*)d_in[1];
  const float* bq = (const float*)d_in[2];
  const float* Wk = (const float*)d_in[3];
  const float* bk = (const float*)d_in[4];
  const float* Wv = (const float*)d_in[5];
  const float* bv = (const float*)d_in[6];
  float* out = (float*)d_out;

  char* ws = (char*)d_ws;
  u16_t* xb  = (u16_t*)(ws);                 // 8 MB   x bf16 [4096][1024]
  u16_t* Wt  = (u16_t*)(ws + 8388608);       // 6 MB   Wt bf16 [3072][1024]
  u16_t* Qb  = (u16_t*)(ws + 14680064);      // 8 MB   Q bf16 [bh][s][dk] (pre-scaled)
  u16_t* Kb  = (u16_t*)(ws + 23068672);      // 8 MB   K bf16 [bh][s][dk]
  u16_t* Vtb = (u16_t*)(ws + 31457280);      // 8 MB   V^T bf16 [bh][dk][s]

  hipLaunchKernelGGL(k_prep, dim3(4864), dim3(256), 0, stream, x, Wq, Wk, Wv, xb, Wt);
  hipLaunchKernelGGL(k_gemm_qkv, dim3(24, 32), dim3(256), 0, stream,
                     xb, Wt, bq, bk, bv, Qb, Kb, Vtb);
  hipLaunchKernelGGL(k_attn, dim3(1024), dim3(128), 0, stream, Qb, Kb, Vtb, out);
}

// Round 8
// 168.338 us; speedup vs baseline: 1.0941x; 1.0941x over previous
//
#include <hip/hip_runtime.h>
#include <hip/hip_bf16.h>
#include <stdint.h>

typedef __bf16 bf16x8 __attribute__((ext_vector_type(8)));
typedef __bf16 bf16x4 __attribute__((ext_vector_type(4)));
typedef float  f32x4  __attribute__((ext_vector_type(4)));
typedef short  s16x4  __attribute__((ext_vector_type(4)));
typedef unsigned short u16_t;

#define MFMA(a, b, c)   __builtin_amdgcn_mfma_f32_16x16x32_bf16((a), (b), (c), 0, 0, 0)
#define MFMA16(a, b, c) __builtin_amdgcn_mfma_f32_16x16x16bf16_1k((a), (b), (c), 0, 0, 0)

// async global->LDS, 16B per lane; LDS dest is wave-uniform base + lane*16
__device__ __forceinline__ void cp16(const void* g, void* l) {
  __builtin_amdgcn_global_load_lds(
      (const __attribute__((address_space(1))) unsigned int*)g,
      (__attribute__((address_space(3))) unsigned int*)l, 16, 0, 0);
}

// ---------------- kernel 1: fused x-convert + W-transpose-convert ----------------
__global__ __launch_bounds__(256) void k_prep(const float* __restrict__ x,
                                              const float* __restrict__ W0,
                                              const float* __restrict__ W1,
                                              const float* __restrict__ W2,
                                              u16_t* __restrict__ xb,
                                              u16_t* __restrict__ Wt) {
  __shared__ u16_t T[64][65];
  int bx = blockIdx.x, t = threadIdx.x;
  if (bx < 4096) {
    int i = bx * 256 + t;
    float4 f = ((const float4*)x)[i];
    bf16x4 o = {(__bf16)f.x, (__bf16)f.y, (__bf16)f.z, (__bf16)f.w};
    *(bf16x4*)&xb[(size_t)i * 4] = o;
    return;
  }
  int j = bx - 4096;
  int nx = j & 15, ny = (j >> 4) & 15, z = j >> 8;
  const float* W = z == 0 ? W0 : (z == 1 ? W1 : W2);
  int k0 = ny * 64, n0 = nx * 64;
#pragma unroll
  for (int i = 0; i < 16; i++) {
    int e = i * 256 + t, r = e >> 6, c = e & 63;
    __bf16 hv = (__bf16)W[(size_t)(k0 + r) * 1024 + n0 + c];
    T[r][c] = *(u16_t*)&hv;
  }
  __syncthreads();
  size_t base = ((size_t)z * 1024 + n0) * 1024 + k0;
#pragma unroll
  for (int i = 0; i < 16; i++) {
    int e = i * 256 + t, r = e >> 6, c = e & 63;
    Wt[base + (size_t)r * 1024 + c] = T[c][r];
  }
}

// ---------------- kernel 2: fused QKV GEMM (BK=64) ----------------
// C[4096,3072] = A[4096,1024] @ Bt[3072,1024]^T, +bias.
// Q: *log2(e)/8 pre-scale, [bh][s][dk]. K: [bh][s][dk]. V: transposed [bh][dk][s].
__global__ __launch_bounds__(256, 4) void k_gemm_qkv(
    const u16_t* __restrict__ A, const u16_t* __restrict__ Bt,
    const float* __restrict__ bq, const float* __restrict__ bk,
    const float* __restrict__ bv,
    u16_t* __restrict__ Qo, u16_t* __restrict__ Ko, u16_t* __restrict__ Vo) {
  __shared__ u16_t As[128 * 64];   // 16 KB, rows of 64 hw, chunk-XOR swizzled
  __shared__ u16_t Bs[128 * 64];   // 16 KB
  const int tid = threadIdx.x, lane = tid & 63, wv = tid >> 6;
  const int quad = lane >> 4, col = lane & 15;
  const int wm = wv >> 1, wn = wv & 1;
  const int tn = blockIdx.x * 128, tm = blockIdx.y * 128;
  f32x4 acc[4][4] = {};

  const int r8 = lane >> 3, c8 = lane & 7;  // staging: row-in-block, phys chunk
  const int lch = c8 ^ r8;                  // global chunk to fetch

  for (int kk = 0; kk < 1024; kk += 64) {
#pragma unroll
    for (int i = 0; i < 4; i++) {
      int blk = wv * 4 + i;          // 16 blocks of 8 rows
      int m = blk * 8 + r8;
      cp16(A + (size_t)(tm + m) * 1024 + kk + lch * 8, As + blk * 512 + lane * 8);
      cp16(Bt + (size_t)(tn + m) * 1024 + kk + lch * 8, Bs + blk * 512 + lane * 8);
    }
    __syncthreads();
#pragma unroll
    for (int ks = 0; ks < 2; ks++) {
      bf16x8 af[4], bfv[4];
#pragma unroll
      for (int mt = 0; mt < 4; mt++) {
        int row = wm * 64 + mt * 16 + col;
        af[mt] = *(const bf16x8*)&As[row * 64 + (((ks * 4 + quad) ^ (row & 7)) * 8)];
      }
#pragma unroll
      for (int nt = 0; nt < 4; nt++) {
        int row = wn * 64 + nt * 16 + col;
        bfv[nt] = *(const bf16x8*)&Bs[row * 64 + (((ks * 4 + quad) ^ (row & 7)) * 8)];
      }
#pragma unroll
      for (int mt = 0; mt < 4; mt++)
#pragma unroll
        for (int nt = 0; nt < 4; nt++)
          acc[mt][nt] = MFMA(af[mt], bfv[nt], acc[mt][nt]);
    }
    __syncthreads();
  }

  const int mat = tn >> 10;
  const float* bias = mat == 0 ? bq : (mat == 1 ? bk : bv);
  if (mat == 2) {
#pragma unroll
    for (int nt = 0; nt < 4; nt++) {
      int gn = tn + wn * 64 + nt * 16 + col;
      int d = gn & 1023, h = d >> 6, dk = d & 63;
      float bb = bias[d];
#pragma unroll
      for (int mt = 0; mt < 4; mt++) {
        int gm = tm + wm * 64 + mt * 16 + quad * 4;
        int b = gm >> 11, s = gm & 2047;
        bf16x4 pk4;
#pragma unroll
        for (int r = 0; r < 4; r++) pk4[r] = (__bf16)(acc[mt][nt][r] + bb);
        *(bf16x4*)&Vo[((size_t)((b * 16 + h) * 64 + dk)) * 2048 + s] = pk4;
      }
    }
  } else {
    u16_t* O = mat == 0 ? Qo : Ko;
    const float scl = mat == 0 ? 0.18033688011112042f : 1.0f;  // log2(e)/8 in Q
#pragma unroll
    for (int nt = 0; nt < 4; nt++) {
      int gn = tn + wn * 64 + nt * 16 + col;
      int d = gn & 1023, h = d >> 6, dk = d & 63;
      float bb = bias[d];
#pragma unroll
      for (int mt = 0; mt < 4; mt++) {
#pragma unroll
        for (int r = 0; r < 4; r++) {
          int gm = tm + wm * 64 + mt * 16 + quad * 4 + r;
          int b = gm >> 11, s = gm & 2047;
          __bf16 hv = (__bf16)((acc[mt][nt][r] + bb) * scl);
          O[((size_t)((b * 16 + h) * 2048 + s)) * 64 + dk] = *(u16_t*)&hv;
        }
      }
    }
  }
}

// ---------------- kernel 3: fused attention (v8 = v5 + XCD swizzle + unroll) ----------------
// 4 waves (qh x kh), wave = 32q x 32k per 64-key stage; P in registers
// (S^T C-layout == 16x16x16 A-layout identity); 40KB LDS, 4 blocks/CU.
__global__ __launch_bounds__(256, 4) void k_attn(const u16_t* __restrict__ Q,
                                                 const u16_t* __restrict__ K,
                                                 const u16_t* __restrict__ Vt,
                                                 float* __restrict__ out) {
  __shared__ u16_t smem[20480];        // 40 KB
  u16_t* Qs  = smem;                   // 8 KB: Q staging (then reduction buffer)
  u16_t* Ksb = smem + 4096;            // 16 KB dbuf: K tiles [64k][64d]
  u16_t* Vsb = smem + 12288;           // 16 KB dbuf: V^T tiles [64d][64k]
  const int tid = threadIdx.x, lane = tid & 63, wv = tid >> 6;
  const int quad = lane >> 4, col = lane & 15;
  const int qh = wv >> 1, kh = wv & 1;

  // XCD swizzle: bid&7 = XCD, 4 heads per XCD -> K/V (2 MB) fit 4 MB L2
  const int bid = blockIdx.x;
  const int bh = (bid & 7) + 8 * ((bid >> 3) >> 5);
  const int qt = (bid >> 3) & 31;
  const int b = bh >> 4, h = bh & 15;
  const int r8 = lane >> 3, c8 = lane & 7;

  const u16_t* Qg = Q + ((size_t)bh * 2048 + qt * 64) * 64;
  const u16_t* Kg = K + (size_t)bh * 2048 * 64;
  const u16_t* Vg = Vt + (size_t)bh * 64 * 2048;

  // initial staging: Q + K0 + V0 (row&7 chunk-XOR geometry)
#pragma unroll
  for (int i = 0; i < 2; i++) {
    int c = wv * 2 + i;
    int row = c * 8 + r8;
    int lch = c8 ^ r8;
    cp16(Qg + (size_t)row * 64 + lch * 8, Qs + c * 512 + lane * 8);
    cp16(Kg + (size_t)row * 64 + lch * 8, Ksb + c * 512 + lane * 8);
    cp16(Vg + (size_t)row * 2048 + lch * 8, Vsb + c * 512 + lane * 8);
  }
  __syncthreads();

  // Q fragments (this wave's 32 q) -> registers
  bf16x8 qf[2][2];
#pragma unroll
  for (int nt = 0; nt < 2; nt++)
#pragma unroll
    for (int ks = 0; ks < 2; ks++) {
      int row = qh * 32 + nt * 16 + col;
      qf[nt][ks] = *(const bf16x8*)&Qs[row * 64 + (((ks * 4 + quad) ^ (row & 7)) * 8)];
    }

  const short one_bf = (short)0x3F80;  // bf16 1.0
  s16x4 ones4 = {one_bf, one_bf, one_bf, one_bf};

  f32x4 ao[2][4] = {};
  f32x4 dn[2] = {};

#pragma unroll 2
  for (int kt = 0; kt < 32; kt++) {
    const int cur = kt & 1;
    const u16_t* Kc = Ksb + cur * 4096;
    const u16_t* Vc = Vsb + cur * 4096;
    if (kt + 1 < 32) {
      u16_t* Kn = Ksb + (cur ^ 1) * 4096;
      u16_t* Vn = Vsb + (cur ^ 1) * 4096;
#pragma unroll
      for (int i = 0; i < 2; i++) {
        int c = wv * 2 + i;
        int row = c * 8 + r8;
        int lch = c8 ^ r8;
        cp16(Kg + (size_t)(kt + 1) * 4096 + (size_t)row * 64 + lch * 8,
             Kn + c * 512 + lane * 8);
        cp16(Vg + (size_t)row * 2048 + (kt + 1) * 64 + lch * 8,
             Vn + c * 512 + lane * 8);
      }
    }

    // S^T = K @ Q^T for this wave's 32k x 32q block (A=K-frag, B=Q-frag)
    f32x4 sc[2][2] = {};
#pragma unroll
    for (int ks = 0; ks < 2; ks++) {
      bf16x8 kf[2];
#pragma unroll
      for (int mt = 0; mt < 2; mt++) {
        int row = kh * 32 + mt * 16 + col;
        kf[mt] = *(const bf16x8*)&Kc[row * 64 + (((ks * 4 + quad) ^ (row & 7)) * 8)];
      }
#pragma unroll
      for (int mt = 0; mt < 2; mt++)
#pragma unroll
        for (int nt = 0; nt < 2; nt++)
          sc[mt][nt] = MFMA(kf[mt], qf[nt][ks], sc[mt][nt]);
    }

    // P = exp2(S^T) in-register -> bf16x4 = A-fragment of 16x16x16 directly
    s16x4 pf[2][2];
#pragma unroll
    for (int mt = 0; mt < 2; mt++)
#pragma unroll
      for (int nt = 0; nt < 2; nt++) {
#pragma unroll
        for (int r = 0; r < 4; r++) {
          __bf16 e = (__bf16)__builtin_amdgcn_exp2f(sc[mt][nt][r]);
          pf[mt][nt][r] = *(short*)&e;
        }
        dn[nt] = MFMA16(pf[mt][nt], ones4, dn[nt]);
      }

    // O += P @ V : B-frag = 4 consecutive keys per lane from V^T tile (b64)
#pragma unroll
    for (int mt = 0; mt < 2; mt++) {
#pragma unroll
      for (int dt = 0; dt < 4; dt++) {
        int row = dt * 16 + col;  // d
        int c = kh * 4 + mt * 2 + (quad >> 1);          // logical 16B chunk (keys)
        int addr = row * 64 + ((c ^ (row & 7)) * 8) + (quad & 1) * 4;
        s16x4 vf = *(const s16x4*)&Vc[addr];
#pragma unroll
        for (int nt = 0; nt < 2; nt++)
          ao[nt][dt] = MFMA16(pf[mt][nt], vf, ao[nt][dt]);
      }
    }
    __syncthreads();  // staging dbuf rotation
  }

  // cross-wave merge over kh: kh=1 dumps partials, kh=0 adds + normalizes + stores
  float* red = (float*)(smem + 4096);  // K/V region dead now
  const int rb = (qh * 64 + lane) * 41;
  if (kh == 1) {
#pragma unroll
    for (int nt = 0; nt < 2; nt++) {
#pragma unroll
      for (int dt = 0; dt < 4; dt++)
#pragma unroll
        for (int r = 0; r < 4; r++)
          red[rb + (nt * 4 + dt) * 4 + r] = ao[nt][dt][r];
#pragma unroll
      for (int r = 0; r < 4; r++)
        red[rb + 32 + nt * 4 + r] = dn[nt][r];
    }
  }
  __syncthreads();
  if (kh == 0) {
#pragma unroll
    for (int nt = 0; nt < 2; nt++) {
      float dsum[4];
#pragma unroll
      for (int r = 0; r < 4; r++)
        dsum[r] = dn[nt][r] + red[rb + 32 + nt * 4 + r] + 1e-8f;
#pragma unroll
      for (int dt = 0; dt < 4; dt++) {
#pragma unroll
        for (int r = 0; r < 4; r++) {
          float v = (ao[nt][dt][r] + red[rb + (nt * 4 + dt) * 4 + r]) / dsum[r];
          int s = qt * 64 + qh * 32 + nt * 16 + quad * 4 + r;
          out[((size_t)b * 2048 + s) * 1024 + h * 64 + dt * 16 + col] = v;
        }
      }
    }
  }
}

// ---------------- launcher ----------------
extern "C" void kernel_launch(void* const* d_in, const int* in_sizes, int n_in,
                              void* d_out, int out_size, void* d_ws, size_t ws_size,
                              hipStream_t stream) {
  const float* x  = (const float*)d_in[0];
  const float* Wq = (const float*)d_in[1];
  const float* bq = (const float*)d_in[2];
  const float* Wk = (const float*)d_in[3];
  const float* bk = (const float*)d_in[4];
  const float* Wv = (const float*)d_in[5];
  const float* bv = (const float*)d_in[6];
  float* out = (float*)d_out;

  char* ws = (char*)d_ws;
  u16_t* xb  = (u16_t*)(ws);                 // 8 MB   x bf16 [4096][1024]
  u16_t* Wt  = (u16_t*)(ws + 8388608);       // 6 MB   Wt bf16 [3072][1024]
  u16_t* Qb  = (u16_t*)(ws + 14680064);      // 8 MB   Q bf16 [bh][s][dk] (pre-scaled)
  u16_t* Kb  = (u16_t*)(ws + 23068672);      // 8 MB   K bf16 [bh][s][dk]
  u16_t* Vtb = (u16_t*)(ws + 31457280);      // 8 MB   V^T bf16 [bh][dk][s]

  hipLaunchKernelGGL(k_prep, dim3(4864), dim3(256), 0, stream, x, Wq, Wk, Wv, xb, Wt);
  hipLaunchKernelGGL(k_gemm_qkv, dim3(24, 32), dim3(256), 0, stream,
                     xb, Wt, bq, bk, bv, Qb, Kb, Vtb);
  hipLaunchKernelGGL(k_attn, dim3(1024), dim3(256), 0, stream, Qb, Kb, Vtb, out);
}